// Round 10
// baseline (257.202 us; speedup 1.0000x reference)
//
#include <hip/hip_runtime.h>
#include <hip/hip_bf16.h>
#include <math.h>

// Problem constants
#define B_    256
#define L_    200
#define H_    256
#define MAXT  256
#define SIXH  1536
#define FOURH 1024
#define NPOS  (B_ * L_)   // 51200

typedef __attribute__((ext_vector_type(8))) short short8;
typedef __attribute__((ext_vector_type(4))) float f32x4;

typedef __attribute__((address_space(3))) void lds_void;
typedef const __attribute__((address_space(1))) void gbl_void;

#define ASM_BAR() asm volatile("s_barrier" ::: "memory")
#define VMCNT3()  asm volatile("s_waitcnt vmcnt(3)" ::: "memory")
#define VMCNT0()  asm volatile("s_waitcnt vmcnt(0)" ::: "memory")

// ---------------------------------------------------------------------------
// Parallel exclusive prefix-sum of lengths (R9: was 1-thread serial = ~256
// dependent global-load latencies). 256 threads, shfl_up wave scans + LDS.
// ---------------------------------------------------------------------------
__global__ void scan_offsets(const int* __restrict__ lengths,
                             int* __restrict__ offsets) {
  int t = threadIdx.x;           // 0..255
  int lane = t & 63, wv = t >> 6;
  int len = lengths[t];
  int s = len;
#pragma unroll
  for (int o = 1; o < 64; o <<= 1) {
    int v = __shfl_up(s, o);
    if (lane >= o) s += v;
  }
  __shared__ int wsum[4];
  if (lane == 63) wsum[wv] = s;
  __syncthreads();
  int pre = 0;
#pragma unroll
  for (int k = 0; k < 4; k++)
    if (k < wv) pre += wsum[k];
  s += pre;
  offsets[t] = s - len;  // exclusive
  if (t == 255) offsets[B_] = s;
}

// ---------------------------------------------------------------------------
// Zero the pad rows of x: rows [total, roundup256(total))
// ---------------------------------------------------------------------------
__global__ void zero_pad_x(__hip_bfloat16* __restrict__ x,
                           const int* __restrict__ offsets) {
  int total = offsets[B_];
  int padded = (total + 255) & ~255;
  int row = total + blockIdx.x;
  if (row >= padded) return;
  int t = threadIdx.x;
#pragma unroll
  for (int j = 0; j < 6; j++)
    x[(size_t)row * SIXH + j * 256 + t] = __float2bfloat16(0.0f);
}

// ---------------------------------------------------------------------------
// Per compacted row: absolute output slot b*MAXT+p (or -1).
// ---------------------------------------------------------------------------
__global__ void tpos_kernel(const int* __restrict__ gids,
                            const int* __restrict__ lengths,
                            const int* __restrict__ offsets,
                            int* __restrict__ tpos) {
  int b = blockIdx.x, t = threadIdx.x;
  __shared__ int g[L_];
  int len = lengths[b];
  for (int l = t; l < len; l += 64) g[l] = gids[b * L_ + l];
  __syncthreads();
  if (t != 0) return;
  int base = offsets[b];
  int nsep = 0;
  for (int l = 0; l + 1 < len; l++)
    if (g[l] != g[l + 1]) nsep++;
  int total = len + nsep;
  int off = MAXT - total;
  int sb = 0;
  for (int l = 0; l < len; l++) {
    int ti = off + l + sb;
    tpos[base + l] = (ti >= 0) ? (b * MAXT + ti) : -1;
    if (l + 1 < len && g[l] != g[l + 1]) sb++;
  }
}

// ---------------------------------------------------------------------------
// Fused transpose+bf16 of BOTH weights in one launch.
// w1 [1536][1024] -> w1t [1024][1536]; w2 [1024][256] -> w2t [256][1024]
// ---------------------------------------------------------------------------
__global__ void transpose_both(const float* __restrict__ w1,
                               __hip_bfloat16* __restrict__ w1t,
                               const float* __restrict__ w2,
                               __hip_bfloat16* __restrict__ w2t) {
  __shared__ float tile[32][33];
  int id = blockIdx.x;
  const float* in; __hip_bfloat16* out; int R, C, tc, tr;
  if (id < 1536) {               // w1: tc 0..31 (C/32), tr 0..47 (R/32)
    in = w1; out = w1t; R = 1536; C = 1024; tc = id & 31; tr = id >> 5;
  } else {                       // w2: tc 0..7, tr 0..31
    int j = id - 1536;
    in = w2; out = w2t; R = 1024; C = 256; tc = j & 7; tr = j >> 3;
  }
  int tx = threadIdx.x & 31, ty = threadIdx.x >> 5;  // 32 x 8
#pragma unroll
  for (int i = 0; i < 4; i++)
    tile[ty + i * 8][tx] = in[(size_t)(tr * 32 + ty + i * 8) * C + tc * 32 + tx];
  __syncthreads();
#pragma unroll
  for (int i = 0; i < 4; i++)
    out[(size_t)(tc * 32 + ty + i * 8) * R + tr * 32 + tx] =
        __float2bfloat16(tile[tx][ty + i * 8]);
}

// ---------------------------------------------------------------------------
// Fused embedding gather + concat + LayerNorm -> x bf16 [row][1536]
// ---------------------------------------------------------------------------
__global__ void embed_ln_kernel(const int* __restrict__ tok0,
                                const int* __restrict__ tok1,
                                const int* __restrict__ tok2,
                                const int* __restrict__ tok3,
                                const int* __restrict__ tgap,
                                const int* __restrict__ gid,
                                const int* __restrict__ lengths,
                                const int* __restrict__ offsets,
                                const float* __restrict__ token_emb,
                                const float* __restrict__ tg_emb,
                                const float* __restrict__ g_emb,
                                const float* __restrict__ gamma,
                                const float* __restrict__ beta,
                                __hip_bfloat16* __restrict__ xout) {
  int l = blockIdx.x, b = blockIdx.y;
  if (l >= lengths[b]) return;
  int pos = b * L_ + l;
  int row = offsets[b] + l;
  int t = threadIdx.x;
  int wv = t >> 6;
  int ln = t & 63;
  int c4 = ln * 4;

  const float* tab;
  int idx;
  if (wv == 0)      { tab = token_emb; idx = tok0[pos]; }
  else if (wv == 1) { tab = token_emb; idx = tok1[pos]; }
  else if (wv == 2) { tab = token_emb; idx = tok2[pos]; }
  else if (wv == 3) { tab = token_emb; idx = tok3[pos]; }
  else if (wv == 4) { tab = tg_emb;    idx = min(max(tgap[pos], 0), 64); }
  else              { tab = g_emb;     idx = gid[pos]; }

  float4 v = *(const float4*)&tab[(size_t)idx * H_ + c4];

  float s = v.x + v.y + v.z + v.w;
  float q = v.x * v.x + v.y * v.y + v.z * v.z + v.w * v.w;
#pragma unroll
  for (int o = 32; o; o >>= 1) { s += __shfl_down(s, o); q += __shfl_down(q, o); }
  __shared__ float ps[6], pq[6];
  if (ln == 0) { ps[wv] = s; pq[wv] = q; }
  __syncthreads();
  float ts = 0.f, tq = 0.f;
#pragma unroll
  for (int k = 0; k < 6; k++) { ts += ps[k]; tq += pq[k]; }
  float mu = ts * (1.0f / 1536.0f);
  float var = tq * (1.0f / 1536.0f) - mu * mu;
  float rstd = rsqrtf(var + 1e-5f);

  int cbase = wv * 256 + c4;
  float4 gm = *(const float4*)&gamma[cbase];
  float4 bt = *(const float4*)&beta[cbase];
  float y0 = (v.x - mu) * rstd * gm.x + bt.x;
  float y1 = (v.y - mu) * rstd * gm.y + bt.y;
  float y2 = (v.z - mu) * rstd * gm.z + bt.z;
  float y3 = (v.w - mu) * rstd * gm.w + bt.w;
  __hip_bfloat16 h0 = __float2bfloat16(y0), h1 = __float2bfloat16(y1);
  __hip_bfloat16 h2 = __float2bfloat16(y2), h3 = __float2bfloat16(y3);
  ushort4 pk;
  pk.x = *(unsigned short*)&h0; pk.y = *(unsigned short*)&h1;
  pk.z = *(unsigned short*)&h2; pk.w = *(unsigned short*)&h3;
  *(ushort4*)&xout[(size_t)row * SIXH + cbase] = pk;
}

// ---------------------------------------------------------------------------
// GEMM1 (R10 rebuild): block tile 256x128, 8 waves of SQUARE 64x64 tiles
// (4M x 2N) -> per-wave LDS reads (64+64 rows)*K vs old (128+64): read:MFMA
// ratio 0.75 -> 0.5. BK=32 double-buffer, 48KB LDS + acc[4][4]=64 VGPR +
// __launch_bounds__(512,4) -> 2 blocks/CU co-resident (TLP fills barrier/
// staging stalls; R9's 1 block/CU had none). Same R4-verified XOR-swizzled
// pair-packed regions (256x32 A, 128x32 B), same stage mapping; vmcnt(3)
// counted (3 stage instrs/iter, one iter in flight).
// XCD locality: all 8 n-tiles of an mt share flat&7 (same XCD), preserving
// R8's 64MB FETCH: mt = (j>>3)*8 + xcd, nt = j&7, j = flat>>3.
// ---------------------------------------------------------------------------
__global__ __launch_bounds__(512, 4)
void gemm1_bk32(const __hip_bfloat16* __restrict__ A,
                const __hip_bfloat16* __restrict__ Bt,
                const float* __restrict__ bias,
                __hip_bfloat16* __restrict__ out,
                const int* __restrict__ total_ptr) {
  constexpr int K = SIXH;      // 1536
  constexpr int NS = K / 32;   // 48 K-steps
  constexpr int N = FOURH;     // 1024

  __shared__ __align__(16) char lds[49152];  // A0,A1:16KB @0,16384; B0,B1:8KB @32768,40960

  int total = total_ptr[0];
  int padded = (total + 255) & ~255;
  int num_mt = padded >> 8;

  int flat = blockIdx.y * 8 + blockIdx.x;  // 0..1599
  int xcd = flat & 7;
  int j = flat >> 3;                       // 0..199
  int nt = j & 7;                          // 0..7 (128-col tiles)
  int mt = (j >> 3) * 8 + xcd;             // same-mt siblings share XCD
  if (mt >= num_mt) return;
  int m0 = mt * 256;
  int n0 = nt * 128;

  int tid = threadIdx.x;
  int lane = tid & 63;
  int w = tid >> 6;
  int wave_m = w >> 1;     // 0..3 (64-row slabs)
  int wave_n = w & 1;      // 0..1 (64-col slabs)

  int r15 = lane & 15, g = lane >> 4;
  int slot_r = (((r15 & 1) << 2) | g) ^ (r15 >> 1);
  int lane_off = (r15 >> 1) * 128 + slot_r * 16;

  int s0 = (tid & 7) ^ ((tid >> 3) & 7);
  int scol = (s0 & 3) * 8;
  int row0 = ((tid >> 3) << 1) + (s0 >> 2);  // 0..127

  float bv4[4];
#pragma unroll
  for (int ni = 0; ni < 4; ni++)
    bv4[ni] = bias[n0 + wave_n * 64 + ni * 16 + r15];

#define AREG(d) (lds + (d) * 16384)
#define BREG(d) (lds + 32768 + (d) * 8192)

  // A half-K-tile: 256 rows x 32 cols = 16KB = 2 instrs (rows row0, row0+128)
#define STAGE_A(ks, d)                                                         \
  do {                                                                         \
    __builtin_amdgcn_global_load_lds(                                          \
        (gbl_void*)(A + (size_t)(m0 + row0) * K + (ks) * 32 + scol),           \
        (lds_void*)(AREG(d) + (size_t)tid * 16 % 8192 + 0 * 8192 +             \
                    (tid * 16 / 8192) * 0),                                    \
        16, 0, 0);                                                             \
  } while (0)
#undef STAGE_A
  // (clean versions below)
#define STAGE_A(ks, d)                                                         \
  do {                                                                         \
    __builtin_amdgcn_global_load_lds(                                          \
        (gbl_void*)(A + (size_t)(m0 + row0) * K + (ks) * 32 + scol),           \
        (lds_void*)(AREG(d) + w * 1024), 16, 0, 0);                            \
    __builtin_amdgcn_global_load_lds(                                          \
        (gbl_void*)(A + (size_t)(m0 + row0 + 128) * K + (ks) * 32 + scol),     \
        (lds_void*)(AREG(d) + 8192 + w * 1024), 16, 0, 0);                     \
  } while (0)
  // B half-K-tile: 128 rows x 32 cols = 8KB = 1 instr
#define STAGE_B(ks, d)                                                         \
  __builtin_amdgcn_global_load_lds(                                            \
      (gbl_void*)(Bt + (size_t)(n0 + row0) * K + (ks) * 32 + scol),            \
      (lds_void*)(BREG(d) + w * 1024), 16, 0, 0)

  f32x4 acc[4][4] = {};

  // prologue: ks0 -> slot0 (3 instrs), ks1 -> slot1 (3); vmcnt(3) = ks0 ready
  STAGE_A(0, 0); STAGE_B(0, 0);
  STAGE_A(1, 1); STAGE_B(1, 1);
  VMCNT3();
  ASM_BAR();

  for (int ks = 0; ks < NS; ++ks) {
    int d = ks & 1;
    int kn = (ks + 2 < NS) ? ks + 2 : NS - 1;  // clamped (dead write, harmless)
    char* Ad = AREG(d);
    char* Bd = BREG(d);

    short8 a[4], b[4];
#pragma unroll
    for (int ni = 0; ni < 4; ni++)
      b[ni] = *(const short8*)(Bd + (wave_n * 64 + ni * 16) * 64 + lane_off);
#pragma unroll
    for (int mi = 0; mi < 4; mi++)
      a[mi] = *(const short8*)(Ad + (wave_m * 64 + mi * 16) * 64 + lane_off);
    ASM_BAR();  // all waves' reads of slot d done -> slot d may be restaged

    STAGE_A(kn, d); STAGE_B(kn, d);

    __builtin_amdgcn_s_setprio(1);
#pragma unroll
    for (int mi = 0; mi < 4; mi++)
#pragma unroll
      for (int ni = 0; ni < 4; ni++)
        acc[mi][ni] = __builtin_amdgcn_mfma_f32_16x16x32_bf16(a[mi], b[ni],
                                                              acc[mi][ni], 0, 0, 0);
    __builtin_amdgcn_s_setprio(0);

    VMCNT3();   // retire prev iter's 3 stages (slot d^1, read next iter)
    ASM_BAR();
  }
  VMCNT0();  // drain stale clamped stages before exit

  // epilogue: D mapping col = lane&15, row = 4*(lane>>4)+reg
  int r0 = g * 4;
#pragma unroll
  for (int mi = 0; mi < 4; mi++)
#pragma unroll
    for (int ni = 0; ni < 4; ni++) {
      int col = n0 + wave_n * 64 + ni * 16 + r15;
      float bv = bv4[ni];
#pragma unroll
      for (int r = 0; r < 4; r++) {
        int row = m0 + wave_m * 64 + mi * 16 + r0 + r;
        float v = acc[mi][ni][r] + bv;
        v = v / (1.0f + __expf(-v));  // silu
        out[(size_t)row * N + col] = __float2bfloat16(v);
      }
    }
#undef STAGE_A
#undef STAGE_B
#undef AREG
#undef BREG
}

// ---------------------------------------------------------------------------
// GEMM2 with fused scatter epilogue (proven 128x128 form).
// ---------------------------------------------------------------------------
__global__ void gemm2_scatter(const __hip_bfloat16* __restrict__ A,
                              const __hip_bfloat16* __restrict__ Bt,
                              const float* __restrict__ bias,
                              const int* __restrict__ tpos,
                              const float* __restrict__ pos_emb,
                              float* __restrict__ out,
                              const int* __restrict__ total_ptr,
                              int N, int K) {
  int m0 = blockIdx.y * 128;
  int total = total_ptr[0];
  int padded = (total + 127) & ~127;
  if (m0 >= padded) return;

  __shared__ __hip_bfloat16 As[128 * 64];
  __shared__ __hip_bfloat16 Bs[128 * 64];
  int n0 = blockIdx.x * 128;
  int tid = threadIdx.x;
  int lane = tid & 63, wid = tid >> 6;
  int wm = (wid >> 1) * 64, wn = (wid & 1) * 64;

  int srow = (lane >> 3);
  int scol = (lane & 7) * 8;

  f32x4 acc[4][4] = {};

  for (int k0 = 0; k0 < K; k0 += 64) {
#pragma unroll
    for (int i = 0; i < 4; i++) {
      int c = wid * 4 + i;
      int row = c * 8 + srow;
      __builtin_amdgcn_global_load_lds(
          (gbl_void*)&A[(size_t)(m0 + row) * K + k0 + scol],
          (lds_void*)(As + c * 512), 16, 0, 0);
      __builtin_amdgcn_global_load_lds(
          (gbl_void*)&Bt[(size_t)(n0 + row) * K + k0 + scol],
          (lds_void*)(Bs + c * 512), 16, 0, 0);
    }
    __syncthreads();
#pragma unroll
    for (int kk = 0; kk < 64; kk += 32) {
      short8 a[4], bb[4];
#pragma unroll
      for (int m = 0; m < 4; m++)
        a[m] = *(const short8*)&As[(wm + m * 16 + (lane & 15)) * 64 + kk +
                                   8 * (lane >> 4)];
#pragma unroll
      for (int n = 0; n < 4; n++)
        bb[n] = *(const short8*)&Bs[(wn + n * 16 + (lane & 15)) * 64 + kk +
                                    8 * (lane >> 4)];
#pragma unroll
      for (int m = 0; m < 4; m++)
#pragma unroll
        for (int n = 0; n < 4; n++)
          acc[m][n] = __builtin_amdgcn_mfma_f32_16x16x32_bf16(a[m], bb[n],
                                                              acc[m][n], 0, 0, 0);
    }
    __syncthreads();
  }

  int r0 = (lane >> 4) * 4;
  int cc = lane & 15;
#pragma unroll
  for (int m = 0; m < 4; m++) {
#pragma unroll
    for (int r = 0; r < 4; r++) {
      int row = m0 + wm + m * 16 + r0 + r;
      if (row >= total) continue;
      int pa = tpos[row];
      if (pa < 0) continue;
      int p = pa & (MAXT - 1);
#pragma unroll
      for (int n = 0; n < 4; n++) {
        int col = n0 + wn + n * 16 + cc;
        float v = acc[m][n][r] + bias[col] + pos_emb[p * H_ + col];
        out[(size_t)pa * H_ + col] = v;
      }
    }
  }
}

// ---------------------------------------------------------------------------
// merge2: sep rows (sep_token + pos_emb), zero-fill empty positions, mm.
// ---------------------------------------------------------------------------
__global__ void merge2_kernel(const int* __restrict__ gids,
                              const int* __restrict__ lengths,
                              const float* __restrict__ sep_token,
                              const float* __restrict__ pos_emb,
                              float* __restrict__ out) {
  int b = blockIdx.x, t = threadIdx.x;
  __shared__ signed char src[MAXT];
  __shared__ int g[L_];
  __shared__ int sh_total;
  int len = lengths[b];
  src[t] = 0;
  for (int l = t; l < len; l += 256) g[l] = gids[b * L_ + l];
  __syncthreads();
  if (t == 0) {
    int nsep = 0;
    for (int l = 0; l + 1 < len; l++)
      if (g[l] != g[l + 1]) nsep++;
    int total = len + nsep;
    sh_total = total;
    int off = MAXT - total;
    int sb = 0;
    for (int l = 0; l < len; l++) {
      int ti = off + l + sb;
      if (ti >= 0) src[ti] = 2;
      if (l + 1 < len && g[l] != g[l + 1]) {
        if (ti + 1 >= 0) src[ti + 1] = 1;
        sb++;
      }
    }
  }
  __syncthreads();
  int total = sh_total;
  int mlen = min(total, MAXT);

  int q = t >> 6, lane = t & 63, c4 = lane * 4;
  float4 sep4 = *(const float4*)&sep_token[c4];
  float* orow = out + (size_t)b * MAXT * H_;
  for (int p0 = 0; p0 < MAXT; p0 += 4) {
    int p = p0 + q;
    int s = src[p];
    if (s == 2) continue;
    float4 v;
    if (s == 1) {
      float4 pe = *(const float4*)&pos_emb[p * H_ + c4];
      v.x = sep4.x + pe.x; v.y = sep4.y + pe.y;
      v.z = sep4.z + pe.z; v.w = sep4.w + pe.w;
    } else {
      v.x = 0.f; v.y = 0.f; v.z = 0.f; v.w = 0.f;
    }
    *(float4*)&orow[(size_t)p * H_ + c4] = v;
  }
  float* mm = out + (size_t)B_ * MAXT * H_;
  mm[b * MAXT + t] = (t >= MAXT - mlen) ? 1.0f : 0.0f;
}

// ---------------------------------------------------------------------------
// launch
// ---------------------------------------------------------------------------
extern "C" void kernel_launch(void* const* d_in, const int* in_sizes, int n_in,
                              void* d_out, int out_size, void* d_ws,
                              size_t ws_size, hipStream_t stream) {
  const int* tok0 = (const int*)d_in[0];
  const int* tok1 = (const int*)d_in[1];
  const int* tok2 = (const int*)d_in[2];
  const int* tok3 = (const int*)d_in[3];
  const int* tgap = (const int*)d_in[4];
  const int* gid  = (const int*)d_in[5];
  const int* lengths = (const int*)d_in[6];
  const float* token_emb = (const float*)d_in[7];
  const float* gamma = (const float*)d_in[8];
  const float* beta  = (const float*)d_in[9];
  const float* w1 = (const float*)d_in[10];
  const float* b1 = (const float*)d_in[11];
  const float* w2 = (const float*)d_in[12];
  const float* b2 = (const float*)d_in[13];
  const float* tg_emb = (const float*)d_in[14];
  const float* g_emb  = (const float*)d_in[15];
  const float* pos_emb = (const float*)d_in[16];
  const float* sep_tok = (const float*)d_in[17];

  // workspace layout (bytes):
  //   x     bf16 [<=51200][1536] @ 0          (157,286,400)
  //   tpos  int  [<=51200]       @ 0          (aliases x; written after GEMM1)
  //   h     bf16 [<=51200][1024] @ 157286400  (104,857,600)
  //   w1t   bf16 [1024][1536]    @ 262144000  (  3,145,728)
  //   w2t   bf16 [256][1024]     @ 265289728  (    524,288)
  //   offsets int[257]           @ 265814016  (      1,028)
  const size_t NEEDED = 265815044;
  if (ws_size < NEEDED) return;

  char* ws = (char*)d_ws;
  __hip_bfloat16* x = (__hip_bfloat16*)ws;
  int* tpos = (int*)ws;  // aliases x (x dead after GEMM1)
  __hip_bfloat16* h = (__hip_bfloat16*)(ws + 157286400);
  __hip_bfloat16* w1t = (__hip_bfloat16*)(ws + 262144000);
  __hip_bfloat16* w2t = (__hip_bfloat16*)(ws + 265289728);
  int* offsets = (int*)(ws + 265814016);

  scan_offsets<<<1, 256, 0, stream>>>(lengths, offsets);
  zero_pad_x<<<256, 256, 0, stream>>>(x, offsets);

  transpose_both<<<1792, 256, 0, stream>>>(w1, w1t, w2, w2t);

  embed_ln_kernel<<<dim3(L_, B_), 384, 0, stream>>>(
      tok0, tok1, tok2, tok3, tgap, gid, lengths, offsets, token_emb, tg_emb,
      g_emb, gamma, beta, x);

  // GEMM1: 256x128 tiles, grid (8 nt, 200 mt), early exit beyond padded.
  gemm1_bk32<<<dim3(8, NPOS / 256), 512, 0, stream>>>(x, w1t, b1, h,
                                                      offsets + B_);

  // x now dead -> tpos may overwrite its region
  tpos_kernel<<<B_, 64, 0, stream>>>(gid, lengths, offsets, tpos);

  gemm2_scatter<<<dim3(H_ / 128, NPOS / 128), 256, 0, stream>>>(
      h, w2t, b2, tpos, pos_emb, (float*)d_out, offsets + B_, H_, FOURH);

  merge2_kernel<<<B_, 256, 0, stream>>>(gid, lengths, sep_tok, pos_emb,
                                        (float*)d_out);
}